// Round 6
// baseline (411.288 us; speedup 1.0000x reference)
//
#include <hip/hip_runtime.h>
#include <math.h>

// Problem constants (match reference setup_inputs()).
#define NNODES 10000
#define MPAD   10112           // 79 * 128 (MFMA M-tile padding)
#define NEDGES 80000           // directed edges before self loops
#define ETOT   (NEDGES + NNODES)

typedef __attribute__((ext_vector_type(4))) float f32x4;
typedef __attribute__((ext_vector_type(8))) short bf16x8;
typedef __attribute__((ext_vector_type(4))) unsigned short u16x4;
typedef __attribute__((ext_vector_type(4))) unsigned int u32x4;

__device__ inline unsigned short f2bf(float f) {
    unsigned int u = __float_as_uint(f);
    unsigned int r = (u + 0x7fffu + ((u >> 16) & 1u)) >> 16;
    return (unsigned short)r;
}
__device__ inline float bf2f(unsigned short h) {
    return __uint_as_float(((unsigned int)h) << 16);
}
__device__ inline float lrelu01(float v) { return (v > 0.f) ? v : 0.1f * v; }
__device__ inline float lrelu02(float v) { return (v > 0.f) ? v : 0.2f * v; }

// ---------------------------------------------------------------------------
// CSR build (group edges by destination). Rebuilt every launch (ws poisoned).
// ---------------------------------------------------------------------------
__global__ void count_deg(const int* __restrict__ ei, int* __restrict__ indeg,
                          int E, int n) {
    int i = blockIdx.x * blockDim.x + threadIdx.x;
    if (i >= E + n) return;
    int dst = (i < E) ? ei[E + i] : (i - E);
    atomicAdd(&indeg[dst], 1);
}

__global__ void scan_rowptr(const int* __restrict__ indeg, int* __restrict__ row_ptr,
                            int* __restrict__ cursor, int n) {
    __shared__ int sums[1024];
    int tid = threadIdx.x;
    int per = (n + 1023) / 1024;
    int start = tid * per;
    int end = start + per; if (end > n) end = n;
    int s = 0;
    for (int i = start; i < end; ++i) s += indeg[i];
    sums[tid] = s;
    __syncthreads();
    for (int off = 1; off < 1024; off <<= 1) {
        int v = (tid >= off) ? sums[tid - off] : 0;
        __syncthreads();
        sums[tid] += v;
        __syncthreads();
    }
    int excl = (tid == 0) ? 0 : sums[tid - 1];
    for (int i = start; i < end; ++i) {
        row_ptr[i] = excl;
        cursor[i]  = excl;
        excl += indeg[i];
    }
    if (tid == 1023) row_ptr[n] = sums[1023];
}

__global__ void scatter_edges(const int* __restrict__ ei, int* __restrict__ cursor,
                              int* __restrict__ col, int E, int n) {
    int i = blockIdx.x * blockDim.x + threadIdx.x;
    if (i >= E + n) return;
    int src, dst;
    if (i < E) { src = ei[i]; dst = ei[E + i]; }
    else       { src = i - E; dst = i - E; }
    int pos = atomicAdd(&cursor[dst], 1);
    col[pos] = src;
}

// ---------------------------------------------------------------------------
// fp32 -> bf16 elementwise convert (for x).
// ---------------------------------------------------------------------------
__global__ void convert_bf16(const float* __restrict__ in, unsigned short* __restrict__ out,
                             int n) {
    int i = blockIdx.x * blockDim.x + threadIdx.x;
    if (i < n) out[i] = f2bf(in[i]);
}

// Transpose-convert W[K][N] fp32 -> Wt[N][K] bf16. K,N multiples of 32.
__global__ void transpose_bf16(const float* __restrict__ W, unsigned short* __restrict__ Wt,
                               int K, int N) {
    __shared__ float t[32][33];
    int kb = blockIdx.y * 32, nb = blockIdx.x * 32;
    int tx = threadIdx.x, ty = threadIdx.y;   // 32 x 8
    #pragma unroll
    for (int i = 0; i < 32; i += 8)
        t[ty + i][tx] = W[(size_t)(kb + ty + i) * N + nb + tx];
    __syncthreads();
    #pragma unroll
    for (int i = 0; i < 32; i += 8)
        Wt[(size_t)(nb + ty + i) * K + kb + tx] = f2bf(t[tx][ty + i]);
}

// ---------------------------------------------------------------------------
// bf16 MFMA GEMM: C[MPAD][N] = A[MPAD][K] (bf16) @ Bt[N][K]^T (bf16).
// Tile 128 x NT (NT=64 or 128), 256 threads = 4 waves.
//   NT=64 : wave covers 64x32 (4x2 16x16x32 MFMAs / k-step)
//   NT=128: wave covers 64x64 (4x4 MFMAs / k-step)
// Split-K via gridDim.z: block z handles K range [z*klen, (z+1)*klen), writing
// fp32 partials at offset z*MPAD*N (F32OUT=true). klen=K, z=1 for no split.
// ---------------------------------------------------------------------------
#define GBM 128
#define GBK 32
template <int NT, bool F32OUT>
__global__ __launch_bounds__(256) void gemm_mfma(const unsigned short* __restrict__ A,
                                                 const unsigned short* __restrict__ Bt,
                                                 void* __restrict__ Cv,
                                                 int N, int K, int klen) {
    constexpr int NI = NT / 32;          // N-subtiles per wave
    __shared__ short As[GBM * GBK];
    __shared__ short Bs[NT * GBK];
    int tid  = threadIdx.x;
    int wave = tid >> 6, lane = tid & 63;
    int bm = blockIdx.y * GBM;
    int bn = blockIdx.x * NT;
    int kbeg = blockIdx.z * klen;
    int kend = kbeg + klen;
    int wr = wave >> 1, wc = wave & 1;
    int lrow  = lane >> 2;
    int lkoff = (lane & 3) * 8;
    int row16 = lane & 15;
    int q8    = (lane >> 4) * 8;

    f32x4 acc[4][NI];
    #pragma unroll
    for (int mi = 0; mi < 4; ++mi)
        #pragma unroll
        for (int ni = 0; ni < NI; ++ni) acc[mi][ni] = (f32x4){0.f, 0.f, 0.f, 0.f};

    for (int k0 = kbeg; k0 < kend; k0 += GBK) {
        // stage A: 8 chunks of 16 rows; wave handles chunks wave, wave+4
        #pragma unroll
        for (int i = 0; i < 2; ++i) {
            int c = i * 4 + wave;
            int row = c * 16 + lrow;
            const unsigned short* gp = A + (size_t)(bm + row) * K + k0 + lkoff;
            __builtin_amdgcn_global_load_lds(
                (const __attribute__((address_space(1))) void*)gp,
                (__attribute__((address_space(3))) void*)&As[c * 512], 16, 0, 0);
        }
        // stage Bt: NT/16 chunks of 16 rows
        #pragma unroll
        for (int i = 0; i < NT / 64; ++i) {
            int c = i * 4 + wave;
            int row = c * 16 + lrow;
            const unsigned short* gp = Bt + (size_t)(bn + row) * K + k0 + lkoff;
            __builtin_amdgcn_global_load_lds(
                (const __attribute__((address_space(1))) void*)gp,
                (__attribute__((address_space(3))) void*)&Bs[c * 512], 16, 0, 0);
        }
        __syncthreads();
        bf16x8 af[4], bfr[NI];
        #pragma unroll
        for (int mi = 0; mi < 4; ++mi)
            af[mi] = *(const bf16x8*)&As[(wr * 64 + mi * 16 + row16) * GBK + q8];
        #pragma unroll
        for (int ni = 0; ni < NI; ++ni)
            bfr[ni] = *(const bf16x8*)&Bs[(wc * (NT / 2) + ni * 16 + row16) * GBK + q8];
        #pragma unroll
        for (int mi = 0; mi < 4; ++mi)
            #pragma unroll
            for (int ni = 0; ni < NI; ++ni)
                acc[mi][ni] = __builtin_amdgcn_mfma_f32_16x16x32_bf16(
                    af[mi], bfr[ni], acc[mi][ni], 0, 0, 0);
        __syncthreads();
    }

    // epilogue: C/D layout col = lane&15, row = (lane>>4)*4 + r
    size_t zoff = (size_t)blockIdx.z * MPAD * N;
    int rbase = bm + wr * 64 + (lane >> 4) * 4;
    int cbase = bn + wc * (NT / 2) + (lane & 15);
    #pragma unroll
    for (int mi = 0; mi < 4; ++mi)
        #pragma unroll
        for (int ni = 0; ni < NI; ++ni)
            #pragma unroll
            for (int r = 0; r < 4; ++r) {
                size_t idx = zoff + (size_t)(rbase + mi * 16 + r) * N + cbase + ni * 16;
                if constexpr (F32OUT) ((float*)Cv)[idx] = acc[mi][ni][r];
                else ((unsigned short*)Cv)[idx] = f2bf(acc[mi][ni][r]);
            }
}

// Sum two fp32 split-K partials -> packed bf16x2.
__global__ void reduce2_bf16(const float* __restrict__ P, unsigned int* __restrict__ out,
                             size_t half_f2, int n2) {
    int i = blockIdx.x * blockDim.x + threadIdx.x;
    if (i >= n2) return;
    const float2* p0 = (const float2*)P;
    const float2* p1 = p0 + half_f2;
    float2 a = p0[i], b = p1[i];
    out[i] = (unsigned int)f2bf(a.x + b.x) | ((unsigned int)f2bf(a.y + b.y) << 16);
}

// ---------------------------------------------------------------------------
// Tiny layer-4 GEMM: C[M][16] (bf16) = A[M][128] (bf16) @ W[128][16] (fp32).
// ---------------------------------------------------------------------------
__global__ __launch_bounds__(256) void gemm4(const unsigned short* __restrict__ A,
                                             const float* __restrict__ W,
                                             unsigned short* __restrict__ C, int M) {
    __shared__ float Ws[128 * 16];
    int tid = threadIdx.x;
    for (int i = tid; i < 2048; i += 256) Ws[i] = W[i];
    __syncthreads();
    int node = blockIdx.x * 16 + (tid >> 4);
    int n = tid & 15;
    if (node >= M) return;
    const unsigned short* ap = A + (size_t)node * 128;
    float acc = 0.f;
    #pragma unroll 8
    for (int k = 0; k < 128; ++k)
        acc += bf2f(ap[k]) * Ws[k * 16 + n];
    C[(size_t)node * 16 + n] = f2bf(acc);
}

// ---------------------------------------------------------------------------
// e_src[n,H], e_dst[n,H]: per-(node,head) dot of bf16 h[n,h,:] with a_src/a_dst.
// ---------------------------------------------------------------------------
__global__ __launch_bounds__(64) void attn_halves(const unsigned short* __restrict__ h,
                                                  const float* __restrict__ a_src,
                                                  const float* __restrict__ a_dst,
                                                  float* __restrict__ e_src,
                                                  float* __restrict__ e_dst,
                                                  int H, int C) {
    int wid = blockIdx.x;          // node*H + head
    int head = wid % H;
    int lane = threadIdx.x;
    const unsigned short* hp = h + (size_t)wid * C;
    float s1 = 0.f, s2 = 0.f;
    for (int c0 = lane * 4; c0 < C; c0 += 256) {
        u16x4 hv = *(const u16x4*)&hp[c0];
        f32x4 as = *(const f32x4*)&a_src[head * C + c0];
        f32x4 ad = *(const f32x4*)&a_dst[head * C + c0];
        #pragma unroll
        for (int j = 0; j < 4; ++j) {
            float v = bf2f(hv[j]);
            s1 += v * as[j];
            s2 += v * ad[j];
        }
    }
    #pragma unroll
    for (int off = 32; off; off >>= 1) {
        s1 += __shfl_down(s1, off);
        s2 += __shfl_down(s2, off);
    }
    if (lane == 0) { e_src[wid] = s1; e_dst[wid] = s2; }
}

// ---------------------------------------------------------------------------
// Aggregation kernels. Softmax computed WITHOUT max subtraction (m=0):
// mathematically identical (ratios unchanged); logits bounded (|e| < ~20) so
// exp stays in fp32 range. Single edge-walk: fused denom + weighted gather.
// ---------------------------------------------------------------------------

// Layer-1 (H=10, C=256): one wave per (node, head-pair). Lane covers 8
// contiguous channels of one head; one dwordx4 per edge per lane.
__global__ __launch_bounds__(64) void agg_l1(const unsigned short* __restrict__ h,
                                             const float* __restrict__ e_src,
                                             const float* __restrict__ e_dst,
                                             const int* __restrict__ row_ptr,
                                             const int* __restrict__ col,
                                             const float* __restrict__ bias,
                                             unsigned short* __restrict__ out) {
    const int H = 10;
    int wid  = blockIdx.x;            // node*5 + hp
    int node = wid / 5;
    int hp   = wid - node * 5;
    int lane = threadIdx.x;
    int sub  = lane >> 5;             // 0/1 within head pair
    int head = hp * 2 + sub;
    int cpos = lane & 31;             // 8 channels each
    int rs = row_ptr[node], re = row_ptr[node + 1];
    float edv = e_dst[node * H + head];

    float dn = 0.f;
    float acc[8];
    #pragma unroll
    for (int k = 0; k < 8; ++k) acc[k] = 0.f;
    #pragma unroll 2
    for (int i = rs; i < re; ++i) {
        int s = col[i];
        float w = __expf(lrelu02(e_src[s * H + head] + edv));
        dn += w;
        u32x4 hv = *(const u32x4*)(h + (size_t)s * 2560 + head * 256 + cpos * 8);
        #pragma unroll
        for (int d = 0; d < 4; ++d) {
            acc[2 * d]     += w * bf2f((unsigned short)(hv[d] & 0xffffu));
            acc[2 * d + 1] += w * bf2f((unsigned short)(hv[d] >> 16));
        }
    }
    float rdn = 1.f / (dn + 1e-16f);

    const float* bp = bias + head * 256 + cpos * 8;
    u32x4 o;
    #pragma unroll
    for (int d = 0; d < 4; ++d) {
        float v0 = lrelu01(acc[2 * d] * rdn + bp[2 * d]);
        float v1 = lrelu01(acc[2 * d + 1] * rdn + bp[2 * d + 1]);
        o[d] = (unsigned int)f2bf(v0) | ((unsigned int)f2bf(v1) << 16);
    }
    *(u32x4*)(out + (size_t)node * 2560 + head * 256 + cpos * 8) = o;
}

// Layer-2 (H=8, C=56): one wave per node, 56 active lanes (8 heads x 7 slots).
__global__ __launch_bounds__(64) void agg_l2(const unsigned short* __restrict__ h,
                                             const float* __restrict__ e_src,
                                             const float* __restrict__ e_dst,
                                             const int* __restrict__ row_ptr,
                                             const int* __restrict__ col,
                                             const float* __restrict__ bias,
                                             unsigned short* __restrict__ out) {
    const int H = 8;
    int node = blockIdx.x;
    int lane = threadIdx.x;
    bool act = lane < 56;
    int head = act ? (lane / 7) : 0;
    int cpos = act ? (lane - head * 7) : 0;
    int rs = row_ptr[node], re = row_ptr[node + 1];
    float edv = e_dst[node * H + head];

    float dn = 0.f;
    float acc[8];
    #pragma unroll
    for (int k = 0; k < 8; ++k) acc[k] = 0.f;
    #pragma unroll 2
    for (int i = rs; i < re; ++i) {
        int s = col[i];
        float w = __expf(lrelu02(e_src[s * H + head] + edv));
        dn += w;
        u32x4 hv = *(const u32x4*)(h + (size_t)s * 448 + head * 56 + cpos * 8);
        #pragma unroll
        for (int d = 0; d < 4; ++d) {
            acc[2 * d]     += w * bf2f((unsigned short)(hv[d] & 0xffffu));
            acc[2 * d + 1] += w * bf2f((unsigned short)(hv[d] >> 16));
        }
    }
    float rdn = 1.f / (dn + 1e-16f);

    if (act) {
        const float* bp = bias + head * 56 + cpos * 8;
        u32x4 o;
        #pragma unroll
        for (int d = 0; d < 4; ++d) {
            float v0 = lrelu01(acc[2 * d] * rdn + bp[2 * d]);
            float v1 = lrelu01(acc[2 * d + 1] * rdn + bp[2 * d + 1]);
            o[d] = (unsigned int)f2bf(v0) | ((unsigned int)f2bf(v1) << 16);
        }
        *(u32x4*)(out + (size_t)node * 448 + head * 56 + cpos * 8) = o;
    }
}

// Layer-3 (H=4, C=32): one wave per node, 16 active lanes.
__global__ __launch_bounds__(64) void agg_l3(const unsigned short* __restrict__ h,
                                             const float* __restrict__ e_src,
                                             const float* __restrict__ e_dst,
                                             const int* __restrict__ row_ptr,
                                             const int* __restrict__ col,
                                             const float* __restrict__ bias,
                                             unsigned short* __restrict__ out) {
    const int H = 4;
    int node = blockIdx.x;
    int lane = threadIdx.x;
    bool act = lane < 16;
    int head = (lane >> 2) & 3;
    int cpos = lane & 3;
    int rs = row_ptr[node], re = row_ptr[node + 1];
    float edv = e_dst[node * H + head];

    float dn = 0.f;
    float acc[8];
    #pragma unroll
    for (int k = 0; k < 8; ++k) acc[k] = 0.f;
    #pragma unroll 2
    for (int i = rs; i < re; ++i) {
        int s = col[i];
        float w = __expf(lrelu02(e_src[s * H + head] + edv));
        dn += w;
        u32x4 hv = *(const u32x4*)(h + (size_t)s * 128 + head * 32 + cpos * 8);
        #pragma unroll
        for (int d = 0; d < 4; ++d) {
            acc[2 * d]     += w * bf2f((unsigned short)(hv[d] & 0xffffu));
            acc[2 * d + 1] += w * bf2f((unsigned short)(hv[d] >> 16));
        }
    }
    float rdn = 1.f / (dn + 1e-16f);

    if (act) {
        const float* bp = bias + head * 32 + cpos * 8;
        u32x4 o;
        #pragma unroll
        for (int d = 0; d < 4; ++d) {
            float v0 = lrelu01(acc[2 * d] * rdn + bp[2 * d]);
            float v1 = lrelu01(acc[2 * d + 1] * rdn + bp[2 * d + 1]);
            o[d] = (unsigned int)f2bf(v0) | ((unsigned int)f2bf(v1) << 16);
        }
        *(u32x4*)(out + (size_t)node * 128 + head * 32 + cpos * 8) = o;
    }
}

// Layer-4 fused: aggregate (H=1, C=16) + bias + LeakyReLU(0.1) + row softmax.
__global__ __launch_bounds__(64) void agg4_softmax(const unsigned int* __restrict__ h2,
                                                   const float* __restrict__ e_src,
                                                   const float* __restrict__ e_dst,
                                                   const int* __restrict__ row_ptr,
                                                   const int* __restrict__ col,
                                                   const float* __restrict__ bias,
                                                   float* __restrict__ out) {
    int node = blockIdx.x;
    int lane = threadIdx.x;
    int cpos = lane & 7;
    int rs = row_ptr[node], re = row_ptr[node + 1];
    float edv = e_dst[node];

    float dn = 0.f, a0 = 0.f, a1 = 0.f;
    for (int i = rs; i < re; ++i) {
        int s = col[i];
        float w = __expf(lrelu02(e_src[s] + edv));
        dn += w;
        unsigned int hv = h2[(size_t)s * 8 + cpos];
        a0 += w * bf2f((unsigned short)(hv & 0xffffu));
        a1 += w * bf2f((unsigned short)(hv >> 16));
    }
    float rdn = 1.f / (dn + 1e-16f);
    float v0 = lrelu01(a0 * rdn + bias[2 * cpos]);
    float v1 = lrelu01(a1 * rdn + bias[2 * cpos + 1]);

    // softmax over 16 values per aligned 8-lane group
    float m = fmaxf(v0, v1);
    #pragma unroll
    for (int off = 4; off; off >>= 1) m = fmaxf(m, __shfl_xor(m, off));
    float e0 = __expf(v0 - m), e1 = __expf(v1 - m);
    float s = e0 + e1;
    #pragma unroll
    for (int off = 4; off; off >>= 1) s += __shfl_xor(s, off);
    float r = 1.f / s;
    if (lane < 8) {
        out[node * 16 + 2 * cpos]     = e0 * r;
        out[node * 16 + 2 * cpos + 1] = e1 * r;
    }
}

// ---------------------------------------------------------------------------
extern "C" void kernel_launch(void* const* d_in, const int* in_sizes, int n_in,
                              void* d_out, int out_size, void* d_ws, size_t ws_size,
                              hipStream_t stream) {
    const float* x   = (const float*)d_in[0];
    const int*   ei  = (const int*)d_in[1];
    const float* W1  = (const float*)d_in[2];
    const float* as1 = (const float*)d_in[3];
    const float* ad1 = (const float*)d_in[4];
    const float* b1  = (const float*)d_in[5];
    const float* W2  = (const float*)d_in[6];
    const float* as2 = (const float*)d_in[7];
    const float* ad2 = (const float*)d_in[8];
    const float* b2  = (const float*)d_in[9];
    const float* W3  = (const float*)d_in[10];
    const float* as3 = (const float*)d_in[11];
    const float* ad3 = (const float*)d_in[12];
    const float* b3  = (const float*)d_in[13];
    const float* W4  = (const float*)d_in[14];
    const float* as4 = (const float*)d_in[15];
    const float* ad4 = (const float*)d_in[16];
    const float* b4  = (const float*)d_in[17];

    char* ws = (char*)d_ws;
    size_t off = 0;
    auto alloc = [&](size_t bytes) -> void* {
        void* p = ws + off;
        off = (off + bytes + 255) & ~(size_t)255;
        return p;
    };
    unsigned short* hbuf = (unsigned short*)alloc((size_t)MPAD * 2560 * sizeof(short)); // GEMM out / attn input
    unsigned short* abuf = (unsigned short*)alloc((size_t)MPAD * 2560 * sizeof(short)); // bf16 GEMM A input
    float*          pbuf = (float*)alloc((size_t)2 * MPAD * 448 * sizeof(float));       // split-K partials
    unsigned short* W1t  = (unsigned short*)alloc((size_t)2560 * 128 * sizeof(short));
    unsigned short* W2t  = (unsigned short*)alloc((size_t)448 * 2560 * sizeof(short));
    unsigned short* W3t  = (unsigned short*)alloc((size_t)128 * 448 * sizeof(short));
    float* e_src  = (float*)alloc((size_t)NNODES * 10 * sizeof(float));
    float* e_dst  = (float*)alloc((size_t)NNODES * 10 * sizeof(float));
    int* indeg    = (int*)alloc(NNODES * sizeof(int));
    int* row_ptr  = (int*)alloc((NNODES + 1) * sizeof(int));
    int* cursor   = (int*)alloc(NNODES * sizeof(int));
    int* col      = (int*)alloc(ETOT * sizeof(int));
    (void)ws_size;

    // ---- CSR build ----
    hipMemsetAsync(indeg, 0, NNODES * sizeof(int), stream);
    int eb = (ETOT + 255) / 256;
    count_deg<<<eb, 256, 0, stream>>>(ei, indeg, NEDGES, NNODES);
    scan_rowptr<<<1, 1024, 0, stream>>>(indeg, row_ptr, cursor, NNODES);
    scatter_edges<<<eb, 256, 0, stream>>>(ei, cursor, col, NEDGES, NNODES);

    // ---- weight transposes + x convert ----
    transpose_bf16<<<dim3(2560 / 32, 128 / 32), dim3(32, 8), 0, stream>>>(W1, W1t, 128, 2560);
    transpose_bf16<<<dim3(448 / 32, 2560 / 32), dim3(32, 8), 0, stream>>>(W2, W2t, 2560, 448);
    transpose_bf16<<<dim3(128 / 32, 448 / 32), dim3(32, 8), 0, stream>>>(W3, W3t, 448, 128);
    convert_bf16<<<(NNODES * 128 + 255) / 256, 256, 0, stream>>>(x, abuf, NNODES * 128);

    const int Mb = MPAD / GBM;   // 79

    // ---- Layer 1: 128 -> 10 heads x 256, concat ----
    gemm_mfma<128, false><<<dim3(2560 / 128, Mb, 1), 256, 0, stream>>>(
        abuf, W1t, hbuf, 2560, 128, 128);
    attn_halves<<<NNODES * 10, 64, 0, stream>>>(hbuf, as1, ad1, e_src, e_dst, 10, 256);
    agg_l1<<<NNODES * 5, 64, 0, stream>>>(hbuf, e_src, e_dst, row_ptr, col, b1, abuf);

    // ---- Layer 2: 2560 -> 8 heads x 56, concat (split-K=2) ----
    gemm_mfma<64, true><<<dim3(448 / 64, Mb, 2), 256, 0, stream>>>(
        abuf, W2t, pbuf, 448, 2560, 1280);
    {
        int n2 = NNODES * 448 / 2;
        reduce2_bf16<<<(n2 + 255) / 256, 256, 0, stream>>>(
            pbuf, (unsigned int*)hbuf, (size_t)MPAD * 448 / 2, n2);
    }
    attn_halves<<<NNODES * 8, 64, 0, stream>>>(hbuf, as2, ad2, e_src, e_dst, 8, 56);
    agg_l2<<<NNODES, 64, 0, stream>>>(hbuf, e_src, e_dst, row_ptr, col, b2, abuf);

    // ---- Layer 3: 448 -> 4 heads x 32, concat ----
    gemm_mfma<64, false><<<dim3(128 / 64, Mb, 1), 256, 0, stream>>>(
        abuf, W3t, hbuf, 128, 448, 448);
    attn_halves<<<NNODES * 4, 64, 0, stream>>>(hbuf, as3, ad3, e_src, e_dst, 4, 32);
    agg_l3<<<NNODES, 64, 0, stream>>>(hbuf, e_src, e_dst, row_ptr, col, b3, abuf);

    // ---- Layer 4: 128 -> 1 head x 16, mean(=identity), + softmax fused ----
    gemm4<<<(NNODES + 15) / 16, 256, 0, stream>>>(abuf, W4, hbuf, NNODES);
    attn_halves<<<NNODES, 64, 0, stream>>>(hbuf, as4, ad4, e_src, e_dst, 1, 16);
    agg4_softmax<<<NNODES, 64, 0, stream>>>(
        (const unsigned int*)hbuf, e_src, e_dst, row_ptr, col, b4, (float*)d_out);
}

// Round 7
// 353.343 us; speedup vs baseline: 1.1640x; 1.1640x over previous
//
#include <hip/hip_runtime.h>
#include <math.h>

// Problem constants (match reference setup_inputs()).
#define NNODES 10000
#define MPAD   10112           // 79 * 128 (MFMA M-tile padding)
#define NEDGES 80000           // directed edges before self loops
#define ETOT   (NEDGES + NNODES)

typedef __attribute__((ext_vector_type(4))) float f32x4;
typedef __attribute__((ext_vector_type(8))) short bf16x8;
typedef __attribute__((ext_vector_type(4))) unsigned short u16x4;
typedef __attribute__((ext_vector_type(4))) unsigned int u32x4;

__device__ inline unsigned short f2bf(float f) {
    unsigned int u = __float_as_uint(f);
    unsigned int r = (u + 0x7fffu + ((u >> 16) & 1u)) >> 16;
    return (unsigned short)r;
}
__device__ inline float bf2f(unsigned short h) {
    return __uint_as_float(((unsigned int)h) << 16);
}
__device__ inline float lrelu01(float v) { return (v > 0.f) ? v : 0.1f * v; }
__device__ inline float lrelu02(float v) { return (v > 0.f) ? v : 0.2f * v; }

// ---------------------------------------------------------------------------
// CSR build (group edges by destination). Rebuilt every launch (ws poisoned).
// ---------------------------------------------------------------------------
__global__ void count_deg(const int* __restrict__ ei, int* __restrict__ indeg,
                          int E, int n) {
    int i = blockIdx.x * blockDim.x + threadIdx.x;
    if (i >= E + n) return;
    int dst = (i < E) ? ei[E + i] : (i - E);
    atomicAdd(&indeg[dst], 1);
}

__global__ void scan_rowptr(const int* __restrict__ indeg, int* __restrict__ row_ptr,
                            int* __restrict__ cursor, int n) {
    __shared__ int sums[1024];
    int tid = threadIdx.x;
    int per = (n + 1023) / 1024;
    int start = tid * per;
    int end = start + per; if (end > n) end = n;
    int s = 0;
    for (int i = start; i < end; ++i) s += indeg[i];
    sums[tid] = s;
    __syncthreads();
    for (int off = 1; off < 1024; off <<= 1) {
        int v = (tid >= off) ? sums[tid - off] : 0;
        __syncthreads();
        sums[tid] += v;
        __syncthreads();
    }
    int excl = (tid == 0) ? 0 : sums[tid - 1];
    for (int i = start; i < end; ++i) {
        row_ptr[i] = excl;
        cursor[i]  = excl;
        excl += indeg[i];
    }
    if (tid == 1023) row_ptr[n] = sums[1023];
}

__global__ void scatter_edges(const int* __restrict__ ei, int* __restrict__ cursor,
                              int* __restrict__ col, int E, int n) {
    int i = blockIdx.x * blockDim.x + threadIdx.x;
    if (i >= E + n) return;
    int src, dst;
    if (i < E) { src = ei[i]; dst = ei[E + i]; }
    else       { src = i - E; dst = i - E; }
    int pos = atomicAdd(&cursor[dst], 1);
    col[pos] = src;
}

// ---------------------------------------------------------------------------
// fp32 -> bf16 elementwise convert (for x).
// ---------------------------------------------------------------------------
__global__ void convert_bf16(const float* __restrict__ in, unsigned short* __restrict__ out,
                             int n) {
    int i = blockIdx.x * blockDim.x + threadIdx.x;
    if (i < n) out[i] = f2bf(in[i]);
}

// Transpose-convert W[K][N] fp32 -> Wt[N][K] bf16. K,N multiples of 32.
__global__ void transpose_bf16(const float* __restrict__ W, unsigned short* __restrict__ Wt,
                               int K, int N) {
    __shared__ float t[32][33];
    int kb = blockIdx.y * 32, nb = blockIdx.x * 32;
    int tx = threadIdx.x, ty = threadIdx.y;   // 32 x 8
    #pragma unroll
    for (int i = 0; i < 32; i += 8)
        t[ty + i][tx] = W[(size_t)(kb + ty + i) * N + nb + tx];
    __syncthreads();
    #pragma unroll
    for (int i = 0; i < 32; i += 8)
        Wt[(size_t)(nb + ty + i) * K + kb + tx] = f2bf(t[tx][ty + i]);
}

// ---------------------------------------------------------------------------
// bf16 MFMA GEMM: C[MPAD][N] (bf16) = A[MPAD][K] (bf16) @ Bt[N][K]^T (bf16).
// Tile 128 x NT (NT=64 or 128), 256 threads = 4 waves.
// SWIZ: 1-D grid; all N-tiles of one M-tile map to the SAME XCD (b%8
// heuristic) so the A-slice is served from one XCD's L2 instead of being
// re-fetched from HBM by every XCD.
// ---------------------------------------------------------------------------
#define GBM 128
#define GBK 32
template <int NT, bool SWIZ>
__global__ __launch_bounds__(256) void gemm_mfma(const unsigned short* __restrict__ A,
                                                 const unsigned short* __restrict__ Bt,
                                                 unsigned short* __restrict__ C,
                                                 int N, int K) {
    constexpr int NI = NT / 32;          // N-subtiles per wave
    __shared__ short As[GBM * GBK];
    __shared__ short Bs[NT * GBK];
    int bn, bm;
    if constexpr (SWIZ) {
        int b = blockIdx.x;
        int x = b & 7, t = b >> 3;
        int nbn = N / NT;
        int j = x + 8 * (t / nbn);       // M-tile index, fixed mod 8 per XCD
        if (j >= MPAD / GBM) return;
        bn = (t % nbn) * NT;
        bm = j * GBM;
    } else {
        bn = blockIdx.x * NT;
        bm = blockIdx.y * GBM;
    }
    int tid  = threadIdx.x;
    int wave = tid >> 6, lane = tid & 63;
    int wr = wave >> 1, wc = wave & 1;
    int lrow  = lane >> 2;
    int lkoff = (lane & 3) * 8;
    int row16 = lane & 15;
    int q8    = (lane >> 4) * 8;

    f32x4 acc[4][NI];
    #pragma unroll
    for (int mi = 0; mi < 4; ++mi)
        #pragma unroll
        for (int ni = 0; ni < NI; ++ni) acc[mi][ni] = (f32x4){0.f, 0.f, 0.f, 0.f};

    for (int k0 = 0; k0 < K; k0 += GBK) {
        // stage A: 8 chunks of 16 rows; wave handles chunks wave, wave+4
        #pragma unroll
        for (int i = 0; i < 2; ++i) {
            int c = i * 4 + wave;
            int row = c * 16 + lrow;
            const unsigned short* gp = A + (size_t)(bm + row) * K + k0 + lkoff;
            __builtin_amdgcn_global_load_lds(
                (const __attribute__((address_space(1))) void*)gp,
                (__attribute__((address_space(3))) void*)&As[c * 512], 16, 0, 0);
        }
        // stage Bt: NT/16 chunks of 16 rows
        #pragma unroll
        for (int i = 0; i < NT / 64; ++i) {
            int c = i * 4 + wave;
            int row = c * 16 + lrow;
            const unsigned short* gp = Bt + (size_t)(bn + row) * K + k0 + lkoff;
            __builtin_amdgcn_global_load_lds(
                (const __attribute__((address_space(1))) void*)gp,
                (__attribute__((address_space(3))) void*)&Bs[c * 512], 16, 0, 0);
        }
        __syncthreads();
        bf16x8 af[4], bfr[NI];
        #pragma unroll
        for (int mi = 0; mi < 4; ++mi)
            af[mi] = *(const bf16x8*)&As[(wr * 64 + mi * 16 + row16) * GBK + q8];
        #pragma unroll
        for (int ni = 0; ni < NI; ++ni)
            bfr[ni] = *(const bf16x8*)&Bs[(wc * (NT / 2) + ni * 16 + row16) * GBK + q8];
        #pragma unroll
        for (int mi = 0; mi < 4; ++mi)
            #pragma unroll
            for (int ni = 0; ni < NI; ++ni)
                acc[mi][ni] = __builtin_amdgcn_mfma_f32_16x16x32_bf16(
                    af[mi], bfr[ni], acc[mi][ni], 0, 0, 0);
        __syncthreads();
    }

    // epilogue: C/D layout col = lane&15, row = (lane>>4)*4 + r
    int rbase = bm + wr * 64 + (lane >> 4) * 4;
    int cbase = bn + wc * (NT / 2) + (lane & 15);
    #pragma unroll
    for (int mi = 0; mi < 4; ++mi)
        #pragma unroll
        for (int ni = 0; ni < NI; ++ni)
            #pragma unroll
            for (int r = 0; r < 4; ++r)
                C[(size_t)(rbase + mi * 16 + r) * N + cbase + ni * 16] =
                    f2bf(acc[mi][ni][r]);
}

// ---------------------------------------------------------------------------
// Tiny layer-4 GEMM: C[M][16] (bf16) = A[M][128] (bf16) @ W[128][16] (fp32).
// ---------------------------------------------------------------------------
__global__ __launch_bounds__(256) void gemm4(const unsigned short* __restrict__ A,
                                             const float* __restrict__ W,
                                             unsigned short* __restrict__ C, int M) {
    __shared__ float Ws[128 * 16];
    int tid = threadIdx.x;
    for (int i = tid; i < 2048; i += 256) Ws[i] = W[i];
    __syncthreads();
    int node = blockIdx.x * 16 + (tid >> 4);
    int n = tid & 15;
    if (node >= M) return;
    const unsigned short* ap = A + (size_t)node * 128;
    float acc = 0.f;
    #pragma unroll 8
    for (int k = 0; k < 128; ++k)
        acc += bf2f(ap[k]) * Ws[k * 16 + n];
    C[(size_t)node * 16 + n] = f2bf(acc);
}

// ---------------------------------------------------------------------------
// attn halves, wide rows (layer 1: H=10, C=256 and layer 4: H=1, C=16):
// one wave per (node,head).
// ---------------------------------------------------------------------------
__global__ __launch_bounds__(64) void attn_halves(const unsigned short* __restrict__ h,
                                                  const float* __restrict__ a_src,
                                                  const float* __restrict__ a_dst,
                                                  float* __restrict__ e_src,
                                                  float* __restrict__ e_dst,
                                                  int H, int C) {
    int wid = blockIdx.x;          // node*H + head
    int head = wid % H;
    int lane = threadIdx.x;
    const unsigned short* hp = h + (size_t)wid * C;
    float s1 = 0.f, s2 = 0.f;
    for (int c0 = lane * 4; c0 < C; c0 += 256) {
        u16x4 hv = *(const u16x4*)&hp[c0];
        f32x4 as = *(const f32x4*)&a_src[head * C + c0];
        f32x4 ad = *(const f32x4*)&a_dst[head * C + c0];
        #pragma unroll
        for (int j = 0; j < 4; ++j) {
            float v = bf2f(hv[j]);
            s1 += v * as[j];
            s2 += v * ad[j];
        }
    }
    #pragma unroll
    for (int off = 32; off; off >>= 1) {
        s1 += __shfl_down(s1, off);
        s2 += __shfl_down(s2, off);
    }
    if (lane == 0) { e_src[wid] = s1; e_dst[wid] = s2; }
}

// ---------------------------------------------------------------------------
// attn halves, small C (layers 2/3): one wave per NODE, all heads in-wave.
// LPH = 64/H lanes per head, each lane covers C/LPH channels; reduce within
// the aligned LPH-lane group.
// ---------------------------------------------------------------------------
template <int H, int C>
__global__ __launch_bounds__(64) void attn_small(const unsigned short* __restrict__ h,
                                                 const float* __restrict__ a_src,
                                                 const float* __restrict__ a_dst,
                                                 float* __restrict__ e_src,
                                                 float* __restrict__ e_dst) {
    constexpr int LPH = 64 / H;
    constexpr int CPL = C / LPH;
    int node = blockIdx.x;
    int lane = threadIdx.x;
    int head = lane / LPH;
    int k = lane - head * LPH;
    const unsigned short* hp = h + (size_t)node * (H * C) + head * C + k * CPL;
    const float* as = a_src + head * C + k * CPL;
    const float* ad = a_dst + head * C + k * CPL;
    float s1 = 0.f, s2 = 0.f;
    #pragma unroll
    for (int c = 0; c < CPL; ++c) {
        float v = bf2f(hp[c]);
        s1 += v * as[c];
        s2 += v * ad[c];
    }
    #pragma unroll
    for (int off = LPH / 2; off; off >>= 1) {
        s1 += __shfl_down(s1, off);
        s2 += __shfl_down(s2, off);
    }
    if (k == 0) { e_src[node * H + head] = s1; e_dst[node * H + head] = s2; }
}

// ---------------------------------------------------------------------------
// Aggregation kernels. Softmax computed without max subtraction (m=0):
// mathematically identical (ratios unchanged); logits bounded so exp stays
// in fp32 range. Single edge-walk: fused denom + weighted gather.
// ---------------------------------------------------------------------------

// Layer-1 (H=10, C=256): one wave per (node, head-pair). Lane covers 8
// contiguous channels of one head; one dwordx4 per edge per lane.
__global__ __launch_bounds__(64) void agg_l1(const unsigned short* __restrict__ h,
                                             const float* __restrict__ e_src,
                                             const float* __restrict__ e_dst,
                                             const int* __restrict__ row_ptr,
                                             const int* __restrict__ col,
                                             const float* __restrict__ bias,
                                             unsigned short* __restrict__ out) {
    const int H = 10;
    int wid  = blockIdx.x;            // node*5 + hp
    int node = wid / 5;
    int hp   = wid - node * 5;
    int lane = threadIdx.x;
    int sub  = lane >> 5;             // 0/1 within head pair
    int head = hp * 2 + sub;
    int cpos = lane & 31;             // 8 channels each
    int rs = row_ptr[node], re = row_ptr[node + 1];
    float edv = e_dst[node * H + head];

    float dn = 0.f;
    float acc[8];
    #pragma unroll
    for (int k = 0; k < 8; ++k) acc[k] = 0.f;
    #pragma unroll 2
    for (int i = rs; i < re; ++i) {
        int s = col[i];
        float w = __expf(lrelu02(e_src[s * H + head] + edv));
        dn += w;
        u32x4 hv = *(const u32x4*)(h + (size_t)s * 2560 + head * 256 + cpos * 8);
        #pragma unroll
        for (int d = 0; d < 4; ++d) {
            acc[2 * d]     += w * bf2f((unsigned short)(hv[d] & 0xffffu));
            acc[2 * d + 1] += w * bf2f((unsigned short)(hv[d] >> 16));
        }
    }
    float rdn = 1.f / (dn + 1e-16f);

    const float* bp = bias + head * 256 + cpos * 8;
    u32x4 o;
    #pragma unroll
    for (int d = 0; d < 4; ++d) {
        float v0 = lrelu01(acc[2 * d] * rdn + bp[2 * d]);
        float v1 = lrelu01(acc[2 * d + 1] * rdn + bp[2 * d + 1]);
        o[d] = (unsigned int)f2bf(v0) | ((unsigned int)f2bf(v1) << 16);
    }
    *(u32x4*)(out + (size_t)node * 2560 + head * 256 + cpos * 8) = o;
}

// Layer-2 (H=8, C=56): one wave per node, 56 active lanes (8 heads x 7 slots).
__global__ __launch_bounds__(64) void agg_l2(const unsigned short* __restrict__ h,
                                             const float* __restrict__ e_src,
                                             const float* __restrict__ e_dst,
                                             const int* __restrict__ row_ptr,
                                             const int* __restrict__ col,
                                             const float* __restrict__ bias,
                                             unsigned short* __restrict__ out) {
    const int H = 8;
    int node = blockIdx.x;
    int lane = threadIdx.x;
    bool act = lane < 56;
    int head = act ? (lane / 7) : 0;
    int cpos = act ? (lane - head * 7) : 0;
    int rs = row_ptr[node], re = row_ptr[node + 1];
    float edv = e_dst[node * H + head];

    float dn = 0.f;
    float acc[8];
    #pragma unroll
    for (int k = 0; k < 8; ++k) acc[k] = 0.f;
    #pragma unroll 2
    for (int i = rs; i < re; ++i) {
        int s = col[i];
        float w = __expf(lrelu02(e_src[s * H + head] + edv));
        dn += w;
        u32x4 hv = *(const u32x4*)(h + (size_t)s * 448 + head * 56 + cpos * 8);
        #pragma unroll
        for (int d = 0; d < 4; ++d) {
            acc[2 * d]     += w * bf2f((unsigned short)(hv[d] & 0xffffu));
            acc[2 * d + 1] += w * bf2f((unsigned short)(hv[d] >> 16));
        }
    }
    float rdn = 1.f / (dn + 1e-16f);

    if (act) {
        const float* bp = bias + head * 56 + cpos * 8;
        u32x4 o;
        #pragma unroll
        for (int d = 0; d < 4; ++d) {
            float v0 = lrelu01(acc[2 * d] * rdn + bp[2 * d]);
            float v1 = lrelu01(acc[2 * d + 1] * rdn + bp[2 * d + 1]);
            o[d] = (unsigned int)f2bf(v0) | ((unsigned int)f2bf(v1) << 16);
        }
        *(u32x4*)(out + (size_t)node * 448 + head * 56 + cpos * 8) = o;
    }
}

// Layer-3 (H=4, C=32): one wave per node, 16 active lanes.
__global__ __launch_bounds__(64) void agg_l3(const unsigned short* __restrict__ h,
                                             const float* __restrict__ e_src,
                                             const float* __restrict__ e_dst,
                                             const int* __restrict__ row_ptr,
                                             const int* __restrict__ col,
                                             const float* __restrict__ bias,
                                             unsigned short* __restrict__ out) {
    const int H = 4;
    int node = blockIdx.x;
    int lane = threadIdx.x;
    bool act = lane < 16;
    int head = (lane >> 2) & 3;
    int cpos = lane & 3;
    int rs = row_ptr[node], re = row_ptr[node + 1];
    float edv = e_dst[node * H + head];

    float dn = 0.f;
    float acc[8];
    #pragma unroll
    for (int k = 0; k < 8; ++k) acc[k] = 0.f;
    #pragma unroll 2
    for (int i = rs; i < re; ++i) {
        int s = col[i];
        float w = __expf(lrelu02(e_src[s * H + head] + edv));
        dn += w;
        u32x4 hv = *(const u32x4*)(h + (size_t)s * 128 + head * 32 + cpos * 8);
        #pragma unroll
        for (int d = 0; d < 4; ++d) {
            acc[2 * d]     += w * bf2f((unsigned short)(hv[d] & 0xffffu));
            acc[2 * d + 1] += w * bf2f((unsigned short)(hv[d] >> 16));
        }
    }
    float rdn = 1.f / (dn + 1e-16f);

    if (act) {
        const float* bp = bias + head * 32 + cpos * 8;
        u32x4 o;
        #pragma unroll
        for (int d = 0; d < 4; ++d) {
            float v0 = lrelu01(acc[2 * d] * rdn + bp[2 * d]);
            float v1 = lrelu01(acc[2 * d + 1] * rdn + bp[2 * d + 1]);
            o[d] = (unsigned int)f2bf(v0) | ((unsigned int)f2bf(v1) << 16);
        }
        *(u32x4*)(out + (size_t)node * 128 + head * 32 + cpos * 8) = o;
    }
}

// Layer-4 fused: aggregate (H=1, C=16) + bias + LeakyReLU(0.1) + row softmax.
__global__ __launch_bounds__(64) void agg4_softmax(const unsigned int* __restrict__ h2,
                                                   const float* __restrict__ e_src,
                                                   const float* __restrict__ e_dst,
                                                   const int* __restrict__ row_ptr,
                                                   const int* __restrict__ col,
                                                   const float* __restrict__ bias,
                                                   float* __restrict__ out) {
    int node = blockIdx.x;
    int lane = threadIdx.x;
    int cpos = lane & 7;
    int rs = row_ptr[node], re = row_ptr[node + 1];
    float edv = e_dst[node];

    float dn = 0.f, a0 = 0.f, a1 = 0.f;
    for (int i = rs; i < re; ++i) {
        int s = col[i];
        float w = __expf(lrelu02(e_src[s] + edv));
        dn += w;
        unsigned int hv = h2[(size_t)s * 8 + cpos];
        a0 += w * bf2f((unsigned short)(hv & 0xffffu));
        a1 += w * bf2f((unsigned short)(hv >> 16));
    }
    float rdn = 1.f / (dn + 1e-16f);
    float v0 = lrelu01(a0 * rdn + bias[2 * cpos]);
    float v1 = lrelu01(a1 * rdn + bias[2 * cpos + 1]);

    // softmax over 16 values per aligned 8-lane group
    float m = fmaxf(v0, v1);
    #pragma unroll
    for (int off = 4; off; off >>= 1) m = fmaxf(m, __shfl_xor(m, off));
    float e0 = __expf(v0 - m), e1 = __expf(v1 - m);
    float s = e0 + e1;
    #pragma unroll
    for (int off = 4; off; off >>= 1) s += __shfl_xor(s, off);
    float r = 1.f / s;
    if (lane < 8) {
        out[node * 16 + 2 * cpos]     = e0 * r;
        out[node * 16 + 2 * cpos + 1] = e1 * r;
    }
}

// ---------------------------------------------------------------------------
extern "C" void kernel_launch(void* const* d_in, const int* in_sizes, int n_in,
                              void* d_out, int out_size, void* d_ws, size_t ws_size,
                              hipStream_t stream) {
    const float* x   = (const float*)d_in[0];
    const int*   ei  = (const int*)d_in[1];
    const float* W1  = (const float*)d_in[2];
    const float* as1 = (const float*)d_in[3];
    const float* ad1 = (const float*)d_in[4];
    const float* b1  = (const float*)d_in[5];
    const float* W2  = (const float*)d_in[6];
    const float* as2 = (const float*)d_in[7];
    const float* ad2 = (const float*)d_in[8];
    const float* b2  = (const float*)d_in[9];
    const float* W3  = (const float*)d_in[10];
    const float* as3 = (const float*)d_in[11];
    const float* ad3 = (const float*)d_in[12];
    const float* b3  = (const float*)d_in[13];
    const float* W4  = (const float*)d_in[14];
    const float* as4 = (const float*)d_in[15];
    const float* ad4 = (const float*)d_in[16];
    const float* b4  = (const float*)d_in[17];

    char* ws = (char*)d_ws;
    size_t off = 0;
    auto alloc = [&](size_t bytes) -> void* {
        void* p = ws + off;
        off = (off + bytes + 255) & ~(size_t)255;
        return p;
    };
    unsigned short* hbuf = (unsigned short*)alloc((size_t)MPAD * 2560 * sizeof(short)); // GEMM out / attn input
    unsigned short* abuf = (unsigned short*)alloc((size_t)MPAD * 2560 * sizeof(short)); // bf16 GEMM A input
    unsigned short* W1t  = (unsigned short*)alloc((size_t)2560 * 128 * sizeof(short));
    unsigned short* W2t  = (unsigned short*)alloc((size_t)448 * 2560 * sizeof(short));
    unsigned short* W3t  = (unsigned short*)alloc((size_t)128 * 448 * sizeof(short));
    float* e_src  = (float*)alloc((size_t)NNODES * 10 * sizeof(float));
    float* e_dst  = (float*)alloc((size_t)NNODES * 10 * sizeof(float));
    int* indeg    = (int*)alloc(NNODES * sizeof(int));
    int* row_ptr  = (int*)alloc((NNODES + 1) * sizeof(int));
    int* cursor   = (int*)alloc(NNODES * sizeof(int));
    int* col      = (int*)alloc(ETOT * sizeof(int));
    (void)ws_size;

    // ---- CSR build ----
    hipMemsetAsync(indeg, 0, NNODES * sizeof(int), stream);
    int eb = (ETOT + 255) / 256;
    count_deg<<<eb, 256, 0, stream>>>(ei, indeg, NEDGES, NNODES);
    scan_rowptr<<<1, 1024, 0, stream>>>(indeg, row_ptr, cursor, NNODES);
    scatter_edges<<<eb, 256, 0, stream>>>(ei, cursor, col, NEDGES, NNODES);

    // ---- weight transposes + x convert ----
    transpose_bf16<<<dim3(2560 / 32, 128 / 32), dim3(32, 8), 0, stream>>>(W1, W1t, 128, 2560);
    transpose_bf16<<<dim3(448 / 32, 2560 / 32), dim3(32, 8), 0, stream>>>(W2, W2t, 2560, 448);
    transpose_bf16<<<dim3(128 / 32, 448 / 32), dim3(32, 8), 0, stream>>>(W3, W3t, 448, 128);
    convert_bf16<<<(NNODES * 128 + 255) / 256, 256, 0, stream>>>(x, abuf, NNODES * 128);

    const int Mb = MPAD / GBM;   // 79

    // ---- Layer 1: 128 -> 10 heads x 256, concat ----
    gemm_mfma<128, false><<<dim3(2560 / 128, Mb), 256, 0, stream>>>(
        abuf, W1t, hbuf, 2560, 128);
    attn_halves<<<NNODES * 10, 64, 0, stream>>>(hbuf, as1, ad1, e_src, e_dst, 10, 256);
    agg_l1<<<NNODES * 5, 64, 0, stream>>>(hbuf, e_src, e_dst, row_ptr, col, b1, abuf);

    // ---- Layer 2: 2560 -> 8 heads x 56, concat (XCD-swizzled grid) ----
    gemm_mfma<64, true><<<dim3(8 * 7 * 10), 256, 0, stream>>>(
        abuf, W2t, hbuf, 448, 2560);
    attn_small<8, 56><<<NNODES, 64, 0, stream>>>(hbuf, as2, ad2, e_src, e_dst);
    agg_l2<<<NNODES, 64, 0, stream>>>(hbuf, e_src, e_dst, row_ptr, col, b2, abuf);

    // ---- Layer 3: 448 -> 4 heads x 32, concat ----
    gemm_mfma<64, false><<<dim3(2, Mb), 256, 0, stream>>>(
        abuf, W3t, hbuf, 128, 448);
    attn_small<4, 32><<<NNODES, 64, 0, stream>>>(hbuf, as3, ad3, e_src, e_dst);
    agg_l3<<<NNODES, 64, 0, stream>>>(hbuf, e_src, e_dst, row_ptr, col, b3, abuf);

    // ---- Layer 4: 128 -> 1 head x 16, mean(=identity), + softmax fused ----
    gemm4<<<(NNODES + 15) / 16, 256, 0, stream>>>(abuf, W4, hbuf, NNODES);
    attn_halves<<<NNODES, 64, 0, stream>>>(hbuf, as4, ad4, e_src, e_dst, 1, 16);
    agg4_softmax<<<NNODES, 64, 0, stream>>>(
        (const unsigned int*)hbuf, e_src, e_dst, row_ptr, col, b4, (float*)d_out);
}